// Round 10
// baseline (106.220 us; speedup 1.0000x reference)
//
#include <hip/hip_runtime.h>
#include <cstdint>
#include <cstddef>

#define FMIN_F (-3.402823466e38f)

__device__ __forceinline__ float wave_sum(float v) {
#pragma unroll
    for (int off = 32; off > 0; off >>= 1)
        v += __shfl_down(v, off, 64);
    return v; // valid in lane 0
}

// ---------------- GEMV: X in LDS, W 2-stage pipelined, <=64 VGPR by design --
// R7-R9 post-mortem: allocator pins VGPR at 64 (8-wave occupancy heuristic)
// and guts any design needing more (remat / serialize / spill). This shape
// NEEDS only ~60: acc[4][4]=16, wA+wB=32, transient x=4, addresses ~8.
// X lives in LDS (32KB K-slice x 4 batches); per 16B of W we do 4
// ds_read_b128 (78 B/cy/CU at 5 TB/s W-rate, under the ~85 B/cy LDS ceiling).
// Block: 4 waves; wave: 4 rows x K-slice 2048. 2-way K-split -> reduce.
// part layout: [mat][slice(2)][batch(4)][4096]
template <int NMAT>
__global__ __launch_bounds__(256, 6) void gemv_lds_kernel(
    const float* __restrict__ X,                                  // [4][4096]
    const float* __restrict__ W0, const float* __restrict__ W1,
    const float* __restrict__ W2,
    float* __restrict__ part)
{
    __shared__ float4 sX[4][512];                 // 32 KB
    const int tid = threadIdx.x;
    int bid = blockIdx.x;
    const int mi    = (NMAT == 1) ? 0 : (bid >> 9);
    const int rem   = (NMAT == 1) ? bid : (bid & 511);
    const int slice = rem & 1;
    const int chunk = rem >> 1;                   // 0..255, 16 rows each

    const float4* X4 = (const float4*)X;
    for (int i = tid; i < 2048; i += 256) {
        const int b = i >> 9, j = i & 511;
        sX[b][j] = X4[b * 1024 + slice * 512 + j];
    }
    __syncthreads();

    const int wave = tid >> 6;
    const int lane = tid & 63;
    const int rbase = chunk * 16 + wave * 4;
    const float* W = (mi == 0) ? W0 : (mi == 1) ? W1 : W2;
    const float4* Wr0 = (const float4*)W + (size_t)(rbase + 0) * 1024 + slice * 512;
    const float4* Wr1 = Wr0 + 1024;
    const float4* Wr2 = Wr0 + 2048;
    const float4* Wr3 = Wr0 + 3072;

    float acc[4][4];
#pragma unroll
    for (int r = 0; r < 4; ++r)
#pragma unroll
        for (int b = 0; b < 4; ++b) acc[r][b] = 0.f;

    float4 wA0 = Wr0[lane], wA1 = Wr1[lane], wA2 = Wr2[lane], wA3 = Wr3[lane];
    float4 wB0, wB1, wB2, wB3;

#pragma unroll 1
    for (int u2 = 0; u2 < 4; ++u2) {
        const int pA = u2 * 128 + lane;
        const int pB = pA + 64;
        const int pN = (pA + 128) & 511;          // next A (wraps, in-bounds)
        // prefetch step B
        wB0 = Wr0[pB]; wB1 = Wr1[pB]; wB2 = Wr2[pB]; wB3 = Wr3[pB];
        // compute step A
#pragma unroll
        for (int b = 0; b < 4; ++b) {
            const float4 x = sX[b][pA];
            acc[0][b] += wA0.x * x.x + wA0.y * x.y + wA0.z * x.z + wA0.w * x.w;
            acc[1][b] += wA1.x * x.x + wA1.y * x.y + wA1.z * x.z + wA1.w * x.w;
            acc[2][b] += wA2.x * x.x + wA2.y * x.y + wA2.z * x.z + wA2.w * x.w;
            acc[3][b] += wA3.x * x.x + wA3.y * x.y + wA3.z * x.z + wA3.w * x.w;
        }
        // prefetch next step A
        wA0 = Wr0[pN]; wA1 = Wr1[pN]; wA2 = Wr2[pN]; wA3 = Wr3[pN];
        // compute step B
#pragma unroll
        for (int b = 0; b < 4; ++b) {
            const float4 x = sX[b][pB];
            acc[0][b] += wB0.x * x.x + wB0.y * x.y + wB0.z * x.z + wB0.w * x.w;
            acc[1][b] += wB1.x * x.x + wB1.y * x.y + wB1.z * x.z + wB1.w * x.w;
            acc[2][b] += wB2.x * x.x + wB2.y * x.y + wB2.z * x.z + wB2.w * x.w;
            acc[3][b] += wB3.x * x.x + wB3.y * x.y + wB3.z * x.z + wB3.w * x.w;
        }
    }

#pragma unroll
    for (int r = 0; r < 4; ++r)
#pragma unroll
        for (int b = 0; b < 4; ++b) {
            float v = wave_sum(acc[r][b]);
            if (lane == 0)
                part[(((size_t)mi * 2 + slice) * 4 + b) * 4096 + (rbase + r)] = v;
        }
}

// Sum 2 K-slice partials + bias (+scale for matrix 0)
__global__ __launch_bounds__(256) void gemv_reduce_kernel(
    const float* __restrict__ part,
    const float* __restrict__ B0, const float* __restrict__ B1,
    const float* __restrict__ B2,
    float scale0,
    float* __restrict__ Y)                             // [nmat*4][4096]
{
    const int idx = blockIdx.x * 256 + threadIdx.x;
    const int mi = idx >> 14;
    const int b  = (idx >> 12) & 3;
    const int r  = idx & 4095;
    float s = part[(((size_t)mi * 2 + 0) * 4 + b) * 4096 + r]
            + part[(((size_t)mi * 2 + 1) * 4 + b) * 4096 + r];
    const float* Bs = (mi == 0) ? B0 : (mi == 1) ? B1 : B2;
    s += Bs[r];
    if (mi == 0) s *= scale0;
    Y[((size_t)(mi * 4 + b)) * 4096 + r] = s;
}

// ---------------- Attention phase 1: scores ----------------
__global__ __launch_bounds__(256) void score_kernel(
    const float* __restrict__ qkv,     // [3][4][4096]
    const float* __restrict__ pk,      // [B,H,2048,128]
    const float* __restrict__ amask,   // [B,1,1,2049]
    const float* __restrict__ cam,     // [B*H,1,2049]
    const int* __restrict__ sbp, const int* __restrict__ rbp,
    float* __restrict__ scores)        // [128][512]
{
    constexpr int PAST = 2048, S = 2049, HD = 128;
    const int bh = blockIdx.y;
    const int b  = bh >> 5;
    const int h  = bh & 31;
    const int SB = sbp[0], RB = rbp[0];
    const int NS = SB + 1;
    const int NA = NS + RB + 1;

    const int wave = threadIdx.x >> 6;
    const int lane = threadIdx.x & 63;

    const float* qh   = qkv + (size_t)b * 4096 + h * HD;
    const float* knew = qkv + (size_t)(4 + b) * 4096 + h * HD;
    const float2 ql = ((const float2*)qh)[lane];

#pragma unroll
    for (int j = 0; j < 8; ++j) {
        const int i = blockIdx.x * 32 + j * 4 + wave;
        if (i >= NA) continue;
        const int s = (i < NS) ? i : (PAST - RB + (i - NS));
        const float2* kr = (s < PAST)
            ? (const float2*)(pk + ((size_t)bh * PAST + s) * HD)
            : (const float2*)knew;
        const float2 kk = kr[lane];
        float p = ql.x * kk.x + ql.y * kk.y;
        p = wave_sum(p);
        if (lane == 0) {
            const float m  = cam[(size_t)bh * S + s];
            float sc = fmaxf(p + amask[(size_t)b * S + s], FMIN_F);
            sc = sc * m + (1.0f - m) * FMIN_F;
            scores[(size_t)bh * 512 + i] = sc;
        }
    }
}

// ---------------- Attention phase 2: softmax + coefficient fixups ----------------
__global__ __launch_bounds__(256) void softmax_kernel(
    const float* __restrict__ ps,      // [B*H,2048]
    const int* __restrict__ sbp, const int* __restrict__ rbp,
    float* __restrict__ scores)        // [128][512] in/out
{
    constexpr int PAST = 2048;
    const int bh = blockIdx.x;
    const int SB = sbp[0], RB = rbp[0];
    const int NS = SB + 1;
    const int NA = NS + RB + 1;
    const int tid = threadIdx.x;

    __shared__ float s_c[512];
    __shared__ float s_red[256];
    __shared__ float s_mm;

    for (int i = tid; i < NA; i += 256) s_c[i] = scores[(size_t)bh * 512 + i];

    {
        float part = 0.0f;
        const int cnt = SB + RB;
        for (int i = tid; i < cnt; i += 256) {
            const int idx = (i < SB) ? i : (PAST - RB + (i - SB));
            part += ps[(size_t)bh * PAST + idx];
        }
        s_red[tid] = part;
    }
    __syncthreads();
#pragma unroll
    for (int st = 128; st > 0; st >>= 1) {
        if (tid < st) s_red[tid] += s_red[tid + st];
        __syncthreads();
    }
    if (tid == 0) {
        const float mean = s_red[0] / (float)(SB + RB);
        const float prob = ps[(size_t)bh * PAST + (PAST - RB)] / mean;
        s_mm = (prob > 1.0f) ? (1.0f / 32.0f) : 0.0f;
    }
    __syncthreads();

    float mx = -INFINITY;
    for (int i = tid; i < NA; i += 256) mx = fmaxf(mx, s_c[i]);
    s_red[tid] = mx;
    __syncthreads();
#pragma unroll
    for (int st = 128; st > 0; st >>= 1) {
        if (tid < st) s_red[tid] = fmaxf(s_red[tid], s_red[tid + st]);
        __syncthreads();
    }
    const float gmax = s_red[0];
    __syncthreads();

    float lsum = 0.0f;
    for (int i = tid; i < NA; i += 256) {
        const float e = expf(s_c[i] - gmax);
        s_c[i] = e;
        lsum += e;
    }
    s_red[tid] = lsum;
    __syncthreads();
#pragma unroll
    for (int st = 128; st > 0; st >>= 1) {
        if (tid < st) s_red[tid] += s_red[tid + st];
        __syncthreads();
    }
    const float inv = 1.0f / s_red[0];
    __syncthreads();
    for (int i = tid; i < NA; i += 256) s_c[i] *= inv;
    __syncthreads();

    if (tid == 0) {
        float sm = 0.0f;
#pragma unroll
        for (int j = 1; j <= 32; ++j) sm += s_c[NS + j];
        s_c[NS] += s_mm * sm;       // folded CAM value-merge
        s_c[SB]  = 0.99f;           // pinned col * 0.99 value scale
    }
    __syncthreads();

    for (int i = tid; i < NA; i += 256) scores[(size_t)bh * 512 + i] = s_c[i];
}

// ---------------- Attention phase 3: PV partials ----------------
__global__ __launch_bounds__(256) void pv_kernel(
    const float* __restrict__ qkv,     // for v_new
    const float* __restrict__ pv,      // [B,H,2048,128]
    const float* __restrict__ coeff,   // [128][512]
    const int* __restrict__ sbp, const int* __restrict__ rbp,
    float* __restrict__ partial)       // [128][8][128]
{
    constexpr int PAST = 2048, HD = 128;
    const int bh = blockIdx.y;
    const int b  = bh >> 5;
    const int h  = bh & 31;
    const int SB = sbp[0], RB = rbp[0];
    const int NS = SB + 1;
    const int NA = NS + RB + 1;
    const int CPC = (NA + 7) >> 3;
    const int i0 = blockIdx.x * CPC;
    const int i1 = min(NA, i0 + CPC);

    const int tid  = threadIdx.x;
    const int d    = tid & 127;
    const int half = tid >> 7;

    __shared__ float s_co[64];
    __shared__ float s_red[256];

    if (tid < i1 - i0) s_co[tid] = coeff[(size_t)bh * 512 + i0 + tid];
    __syncthreads();

    const float* vnew = qkv + (size_t)(8 + b) * 4096 + h * HD;

    float acc = 0.0f;
    for (int i = i0 + half; i < i1; i += 2) {
        const int s = (i < NS) ? i : (PAST - RB + (i - NS));
        const float* vr = (s < PAST)
            ? (pv + ((size_t)bh * PAST + s) * HD)
            : vnew;
        acc += s_co[i - i0] * vr[d];
    }
    s_red[tid] = acc;
    __syncthreads();
    if (tid < 128)
        partial[((size_t)bh * 8 + blockIdx.x) * HD + d] = s_red[tid] + s_red[tid + 128];
}

// ---------------- Attention phase 4: reduce partials ----------------
__global__ __launch_bounds__(256) void attn_reduce_kernel(
    const float* __restrict__ partial,  // [128][8][128]
    float* __restrict__ attn_out)       // [4][4096] == [128][128]
{
    const int idx = blockIdx.x * 256 + threadIdx.x;
    const int bh = idx >> 7;
    const int d  = idx & 127;
    float s = 0.0f;
#pragma unroll
    for (int c = 0; c < 8; ++c)
        s += partial[(size_t)bh * 1024 + c * 128 + d];
    attn_out[idx] = s;
}

extern "C" void kernel_launch(void* const* d_in, const int* in_sizes, int n_in,
                              void* d_out, int out_size, void* d_ws, size_t ws_size,
                              hipStream_t stream)
{
    const float* hs = (const float*)d_in[0];
    const float* pk = (const float*)d_in[1];
    const float* pv = (const float*)d_in[2];
    const float* am = (const float*)d_in[3];
    const float* cm = (const float*)d_in[4];
    const float* ps = (const float*)d_in[5];
    const float* Wq = (const float*)d_in[6];
    const float* bq = (const float*)d_in[7];
    const float* Wk = (const float*)d_in[8];
    const float* bk = (const float*)d_in[9];
    const float* Wv = (const float*)d_in[10];
    const float* bv = (const float*)d_in[11];
    const float* Wo = (const float*)d_in[12];
    const float* bo = (const float*)d_in[13];
    const int*   sb = (const int*)d_in[14];
    const int*   rb = (const int*)d_in[15];

    float* qkv   = (float*)d_ws;                   // 49152
    float* aout  = qkv + 3 * 4 * 4096;             // 16384
    float* sc    = aout + 4 * 4096;                // 65536
    float* part  = sc + 128 * 512;                 // 131072
    float* gpart = part + 128 * 8 * 128;           // 3*2*4*4096 = 98304
    float* out   = (float*)d_out;

    const float scaling = 0.08838834764831845f;    // 128^-0.5

    gemv_lds_kernel<3><<<1536, 256, 0, stream>>>(hs, Wq, Wk, Wv, gpart);
    gemv_reduce_kernel<<<192, 256, 0, stream>>>(gpart, bq, bk, bv, scaling, qkv);

    score_kernel<<<dim3(16, 128), 256, 0, stream>>>(qkv, pk, am, cm, sb, rb, sc);
    softmax_kernel<<<128, 256, 0, stream>>>(ps, sb, rb, sc);
    pv_kernel<<<dim3(8, 128), 256, 0, stream>>>(qkv, pv, sc, sb, rb, part);
    attn_reduce_kernel<<<64, 256, 0, stream>>>(part, aout);

    gemv_lds_kernel<1><<<512, 256, 0, stream>>>(aout, Wo, Wo, Wo, gpart);
    gemv_reduce_kernel<<<64, 256, 0, stream>>>(gpart, bo, bo, bo, 1.0f, out);
}

// Round 11
// 97.915 us; speedup vs baseline: 1.0848x; 1.0848x over previous
//
#include <hip/hip_runtime.h>
#include <cstdint>
#include <cstddef>

#define FMIN_F (-3.402823466e38f)

__device__ __forceinline__ float wave_sum(float v) {
#pragma unroll
    for (int off = 32; off > 0; off >>= 1)
        v += __shfl_down(v, off, 64);
    return v; // valid in lane 0
}

// ---------------- GEMV: chip-wide sequential sweep ----------------
// R3/R9/R10 invariant: every "waves own rows" shape = 2.4 TB/s; fast kernels
// in this context (fill 7, copy 6.3, RMSNorm 4.9 TB/s) all do a chip-wide
// SEQUENTIAL SWEEP. This kernel replicates that: unit = quarter-row (4KB
// contiguous); at step i, waves 0..4095 read units i*4096..i*4096+4095 =
// one contiguous 16MB window sliding forward. X (64KB) in LDS; with 64KB
// LDS + 512-thr blocks occupancy is LDS-capped at 16 waves/CU for any
// VGPR<=128, so the allocator's 64-VGPR heuristic can't gut the 2-deep
// W double-buffer (R7-R10 failure mode).
// P layout: P[((mat*4096+r)*4 + b)*4 + qu] (quarter partials).
template <int NMAT>
__global__ __launch_bounds__(512) void gemv_sweep_kernel(
    const float* __restrict__ X,                   // [4][4096]
    const float* __restrict__ W0, const float* __restrict__ W1,
    const float* __restrict__ W2,
    float* __restrict__ P)
{
    __shared__ float4 sX[4][1024];                 // 64 KB, full X
    const int tid = threadIdx.x;
    const float4* X4 = (const float4*)X;
    for (int i = tid; i < 4096; i += 512)
        ((float4*)sX)[i] = X4[i];
    __syncthreads();

    const int wave = tid >> 6;
    const int lane = tid & 63;
    const int wid  = blockIdx.x * 8 + wave;        // 0..4095
    constexpr int NIT = NMAT * 4;                  // units/wave (16384*NMAT/4096)

    // ---- helpers ----
    auto pre = [&](int u, float4* w) {
        const int mat = u >> 14;
        const int wu  = u & 16383;
        const int r   = wu >> 2;
        const int qu  = wu & 3;
        const float* W = (mat == 0) ? W0 : (mat == 1) ? W1 : W2;
        const float4* base = (const float4*)W + (size_t)r * 1024 + qu * 256;
#pragma unroll
        for (int c = 0; c < 4; ++c) w[c] = base[c * 64 + lane];
    };
    auto comp = [&](int u, const float4* w) {
        const int mat = u >> 14;
        const int wu  = u & 16383;
        const int r   = wu >> 2;
        const int qu  = wu & 3;
        float acc[4] = {0.f, 0.f, 0.f, 0.f};
#pragma unroll
        for (int c = 0; c < 4; ++c) {
            const int kq = qu * 256 + c * 64 + lane;
#pragma unroll
            for (int b = 0; b < 4; ++b) {
                const float4 x = sX[b][kq];
                acc[b] += w[c].x * x.x + w[c].y * x.y
                        + w[c].z * x.z + w[c].w * x.w;
            }
        }
#pragma unroll
        for (int b = 0; b < 4; ++b) {
            const float v = wave_sum(acc[b]);
            if (lane == 0)
                P[(((size_t)(mat * 4096 + r)) * 4 + b) * 4 + qu] = v;
        }
    };

    float4 wA[4], wB[4];
    pre(wid, wA);
#pragma unroll 1
    for (int i = 0; i < NIT; i += 2) {
        const int uA = i * 4096 + wid;
        const int uB = uA + 4096;                  // i+1 < NIT (NIT even)
        pre(uB, wB);
        comp(uA, wA);
        const int uN = (i + 2 < NIT) ? (uA + 8192) : wid;  // wrap: discarded
        pre(uN, wA);
        comp(uB, wB);
    }
}

// Sum 4 quarter-partials + bias (+scale for matrix 0)
__global__ __launch_bounds__(256) void gemv_reduce_kernel(
    const float* __restrict__ P,
    const float* __restrict__ B0, const float* __restrict__ B1,
    const float* __restrict__ B2,
    float scale0,
    float* __restrict__ Y)                         // [nmat*4][4096]
{
    const int idx = blockIdx.x * 256 + threadIdx.x;
    const int mi = idx >> 14;
    const int b  = (idx >> 12) & 3;
    const int r  = idx & 4095;
    const size_t base = (((size_t)(mi * 4096 + r)) * 4 + b) * 4;
    float s = P[base] + P[base + 1] + P[base + 2] + P[base + 3];
    const float* Bs = (mi == 0) ? B0 : (mi == 1) ? B1 : B2;
    s += Bs[r];
    if (mi == 0) s *= scale0;
    Y[((size_t)(mi * 4 + b)) * 4096 + r] = s;
}

// ---------------- Attention phase 1: scores ----------------
__global__ __launch_bounds__(256) void score_kernel(
    const float* __restrict__ qkv,     // [3][4][4096]
    const float* __restrict__ pk,      // [B,H,2048,128]
    const float* __restrict__ amask,   // [B,1,1,2049]
    const float* __restrict__ cam,     // [B*H,1,2049]
    const int* __restrict__ sbp, const int* __restrict__ rbp,
    float* __restrict__ scores)        // [128][512]
{
    constexpr int PAST = 2048, S = 2049, HD = 128;
    const int bh = blockIdx.y;
    const int b  = bh >> 5;
    const int h  = bh & 31;
    const int SB = sbp[0], RB = rbp[0];
    const int NS = SB + 1;
    const int NA = NS + RB + 1;

    const int wave = threadIdx.x >> 6;
    const int lane = threadIdx.x & 63;

    const float* qh   = qkv + (size_t)b * 4096 + h * HD;
    const float* knew = qkv + (size_t)(4 + b) * 4096 + h * HD;
    const float2 ql = ((const float2*)qh)[lane];

#pragma unroll
    for (int j = 0; j < 8; ++j) {
        const int i = blockIdx.x * 32 + j * 4 + wave;
        if (i >= NA) continue;
        const int s = (i < NS) ? i : (PAST - RB + (i - NS));
        const float2* kr = (s < PAST)
            ? (const float2*)(pk + ((size_t)bh * PAST + s) * HD)
            : (const float2*)knew;
        const float2 kk = kr[lane];
        float p = ql.x * kk.x + ql.y * kk.y;
        p = wave_sum(p);
        if (lane == 0) {
            const float m  = cam[(size_t)bh * S + s];
            float sc = fmaxf(p + amask[(size_t)b * S + s], FMIN_F);
            sc = sc * m + (1.0f - m) * FMIN_F;
            scores[(size_t)bh * 512 + i] = sc;
        }
    }
}

// ---------------- Attention phase 2: softmax + coefficient fixups ----------------
__global__ __launch_bounds__(256) void softmax_kernel(
    const float* __restrict__ ps,      // [B*H,2048]
    const int* __restrict__ sbp, const int* __restrict__ rbp,
    float* __restrict__ scores)        // [128][512] in/out
{
    constexpr int PAST = 2048;
    const int bh = blockIdx.x;
    const int SB = sbp[0], RB = rbp[0];
    const int NS = SB + 1;
    const int NA = NS + RB + 1;
    const int tid = threadIdx.x;

    __shared__ float s_c[512];
    __shared__ float s_red[256];
    __shared__ float s_mm;

    for (int i = tid; i < NA; i += 256) s_c[i] = scores[(size_t)bh * 512 + i];

    {
        float part = 0.0f;
        const int cnt = SB + RB;
        for (int i = tid; i < cnt; i += 256) {
            const int idx = (i < SB) ? i : (PAST - RB + (i - SB));
            part += ps[(size_t)bh * PAST + idx];
        }
        s_red[tid] = part;
    }
    __syncthreads();
#pragma unroll
    for (int st = 128; st > 0; st >>= 1) {
        if (tid < st) s_red[tid] += s_red[tid + st];
        __syncthreads();
    }
    if (tid == 0) {
        const float mean = s_red[0] / (float)(SB + RB);
        const float prob = ps[(size_t)bh * PAST + (PAST - RB)] / mean;
        s_mm = (prob > 1.0f) ? (1.0f / 32.0f) : 0.0f;
    }
    __syncthreads();

    float mx = -INFINITY;
    for (int i = tid; i < NA; i += 256) mx = fmaxf(mx, s_c[i]);
    s_red[tid] = mx;
    __syncthreads();
#pragma unroll
    for (int st = 128; st > 0; st >>= 1) {
        if (tid < st) s_red[tid] = fmaxf(s_red[tid], s_red[tid + st]);
        __syncthreads();
    }
    const float gmax = s_red[0];
    __syncthreads();

    float lsum = 0.0f;
    for (int i = tid; i < NA; i += 256) {
        const float e = expf(s_c[i] - gmax);
        s_c[i] = e;
        lsum += e;
    }
    s_red[tid] = lsum;
    __syncthreads();
#pragma unroll
    for (int st = 128; st > 0; st >>= 1) {
        if (tid < st) s_red[tid] += s_red[tid + st];
        __syncthreads();
    }
    const float inv = 1.0f / s_red[0];
    __syncthreads();
    for (int i = tid; i < NA; i += 256) s_c[i] *= inv;
    __syncthreads();

    if (tid == 0) {
        float sm = 0.0f;
#pragma unroll
        for (int j = 1; j <= 32; ++j) sm += s_c[NS + j];
        s_c[NS] += s_mm * sm;       // folded CAM value-merge
        s_c[SB]  = 0.99f;           // pinned col * 0.99 value scale
    }
    __syncthreads();

    for (int i = tid; i < NA; i += 256) scores[(size_t)bh * 512 + i] = s_c[i];
}

// ---------------- Attention phase 3: PV partials ----------------
__global__ __launch_bounds__(256) void pv_kernel(
    const float* __restrict__ qkv,     // for v_new
    const float* __restrict__ pv,      // [B,H,2048,128]
    const float* __restrict__ coeff,   // [128][512]
    const int* __restrict__ sbp, const int* __restrict__ rbp,
    float* __restrict__ partial)       // [128][8][128]
{
    constexpr int PAST = 2048, HD = 128;
    const int bh = blockIdx.y;
    const int b  = bh >> 5;
    const int h  = bh & 31;
    const int SB = sbp[0], RB = rbp[0];
    const int NS = SB + 1;
    const int NA = NS + RB + 1;
    const int CPC = (NA + 7) >> 3;
    const int i0 = blockIdx.x * CPC;
    const int i1 = min(NA, i0 + CPC);

    const int tid  = threadIdx.x;
    const int d    = tid & 127;
    const int half = tid >> 7;

    __shared__ float s_co[64];
    __shared__ float s_red[256];

    if (tid < i1 - i0) s_co[tid] = coeff[(size_t)bh * 512 + i0 + tid];
    __syncthreads();

    const float* vnew = qkv + (size_t)(8 + b) * 4096 + h * HD;

    float acc = 0.0f;
    for (int i = i0 + half; i < i1; i += 2) {
        const int s = (i < NS) ? i : (PAST - RB + (i - NS));
        const float* vr = (s < PAST)
            ? (pv + ((size_t)bh * PAST + s) * HD)
            : vnew;
        acc += s_co[i - i0] * vr[d];
    }
    s_red[tid] = acc;
    __syncthreads();
    if (tid < 128)
        partial[((size_t)bh * 8 + blockIdx.x) * HD + d] = s_red[tid] + s_red[tid + 128];
}

// ---------------- Attention phase 4: reduce partials ----------------
__global__ __launch_bounds__(256) void attn_reduce_kernel(
    const float* __restrict__ partial,  // [128][8][128]
    float* __restrict__ attn_out)       // [4][4096] == [128][128]
{
    const int idx = blockIdx.x * 256 + threadIdx.x;
    const int bh = idx >> 7;
    const int d  = idx & 127;
    float s = 0.0f;
#pragma unroll
    for (int c = 0; c < 8; ++c)
        s += partial[(size_t)bh * 1024 + c * 128 + d];
    attn_out[idx] = s;
}

extern "C" void kernel_launch(void* const* d_in, const int* in_sizes, int n_in,
                              void* d_out, int out_size, void* d_ws, size_t ws_size,
                              hipStream_t stream)
{
    const float* hs = (const float*)d_in[0];
    const float* pk = (const float*)d_in[1];
    const float* pv = (const float*)d_in[2];
    const float* am = (const float*)d_in[3];
    const float* cm = (const float*)d_in[4];
    const float* ps = (const float*)d_in[5];
    const float* Wq = (const float*)d_in[6];
    const float* bq = (const float*)d_in[7];
    const float* Wk = (const float*)d_in[8];
    const float* bk = (const float*)d_in[9];
    const float* Wv = (const float*)d_in[10];
    const float* bv = (const float*)d_in[11];
    const float* Wo = (const float*)d_in[12];
    const float* bo = (const float*)d_in[13];
    const int*   sb = (const int*)d_in[14];
    const int*   rb = (const int*)d_in[15];

    float* qkv  = (float*)d_ws;                   // 49152
    float* aout = qkv + 3 * 4 * 4096;             // 16384
    float* sc   = aout + 4 * 4096;                // 65536
    float* part = sc + 128 * 512;                 // 131072
    float* P    = part + 128 * 8 * 128;           // 12288*4*4 = 196608
    float* out  = (float*)d_out;

    const float scaling = 0.08838834764831845f;   // 128^-0.5

    gemv_sweep_kernel<3><<<512, 512, 0, stream>>>(hs, Wq, Wk, Wv, P);
    gemv_reduce_kernel<<<192, 256, 0, stream>>>(P, bq, bk, bv, scaling, qkv);

    score_kernel<<<dim3(16, 128), 256, 0, stream>>>(qkv, pk, am, cm, sb, rb, sc);
    softmax_kernel<<<128, 256, 0, stream>>>(ps, sb, rb, sc);
    pv_kernel<<<dim3(8, 128), 256, 0, stream>>>(qkv, pv, sc, sb, rb, part);
    attn_reduce_kernel<<<64, 256, 0, stream>>>(part, aout);

    gemv_sweep_kernel<1><<<512, 512, 0, stream>>>(aout, Wo, Wo, Wo, P);
    gemv_reduce_kernel<<<64, 256, 0, stream>>>(P, bo, bo, bo, 1.0f, out);
}